// Round 1
// baseline (327.630 us; speedup 1.0000x reference)
//
#include <hip/hip_runtime.h>
#include <math.h>

#define NB   2
#define CIN  256
#define CC   256
#define HH   80
#define WW   80
#define HWSZ 6400
#define GG   16
#define CGN  16
#define OMC  432   // G*K*3 = 16*9*3
#define EPSB 1e-5f

// Tiled fp32 GEMM: C[M,Nc] = A(M,Kd) @ B(Kd,Nc) [+ bias] [+ BN+SiLU]
// MODE 0: + bias, store row-major
// MODE 1: BN+SiLU (no bias), store row-major
// MODE 2: + bias, BN+SiLU, store transposed to NCHW (Cout[(n*CC+c)*HW + p])
// ATRANS: A[m,k] = A[(n_img*Kd + k)*HWSZ + p]  (x in NCHW)
template <int MODE, bool ATRANS>
__global__ __launch_bounds__(256) void gemm_k(
    const float* __restrict__ A, const float* __restrict__ B,
    const float* __restrict__ bias,
    const float* __restrict__ bng, const float* __restrict__ bnb,
    const float* __restrict__ bnm, const float* __restrict__ bnv,
    float* __restrict__ Cout, int M, int Nc, int Kd)
{
    __shared__ float As[16][64];
    __shared__ float Bs[16][64];
    const int t  = threadIdx.x;
    const int m0 = blockIdx.x * 64;
    const int n0 = blockIdx.y * 64;
    const int tx = t & 15, ty = t >> 4;
    const int n_img = m0 / HWSZ;
    const int p0    = m0 % HWSZ;
    float acc[4][4] = {};

    for (int k0 = 0; k0 < Kd; k0 += 16) {
        if (ATRANS) {
#pragma unroll
            for (int j = 0; j < 4; ++j) {
                int e = t + j * 256;
                int k = e >> 6, m = e & 63;
                As[k][m] = A[(size_t)(n_img * Kd + k0 + k) * HWSZ + p0 + m];
            }
        } else {
            int r = t >> 2, kk = (t & 3) * 4;
            const float4 av =
                *reinterpret_cast<const float4*>(&A[(size_t)(m0 + r) * Kd + k0 + kk]);
            As[kk + 0][r] = av.x; As[kk + 1][r] = av.y;
            As[kk + 2][r] = av.z; As[kk + 3][r] = av.w;
        }
#pragma unroll
        for (int j = 0; j < 4; ++j) {
            int e = t + j * 256;
            int k = e >> 6, nn = e & 63;
            int col = n0 + nn;
            Bs[k][nn] = (col < Nc) ? B[(size_t)(k0 + k) * Nc + col] : 0.f;
        }
        __syncthreads();
#pragma unroll
        for (int kk = 0; kk < 16; ++kk) {
            float4 a = *reinterpret_cast<const float4*>(&As[kk][ty * 4]);
            float4 b = *reinterpret_cast<const float4*>(&Bs[kk][tx * 4]);
            float av[4] = {a.x, a.y, a.z, a.w};
            float bw[4] = {b.x, b.y, b.z, b.w};
#pragma unroll
            for (int i = 0; i < 4; ++i)
#pragma unroll
                for (int j = 0; j < 4; ++j) acc[i][j] += av[i] * bw[j];
        }
        __syncthreads();
    }

    if (MODE == 0 || MODE == 1) {
#pragma unroll
        for (int j = 0; j < 4; ++j) {
            int col = n0 + tx * 4 + j;
            if (col >= Nc) continue;
            float bb = (MODE == 0) ? bias[col] : 0.f;
            float mu = 0.f, iv = 0.f, gm = 0.f, bt = 0.f;
            if (MODE == 1) {
                mu = bnm[col]; iv = rsqrtf(bnv[col] + EPSB);
                gm = bng[col]; bt = bnb[col];
            }
#pragma unroll
            for (int i = 0; i < 4; ++i) {
                float v = acc[i][j] + bb;
                if (MODE == 1) {
                    v = (v - mu) * iv * gm + bt;
                    v = v / (1.f + expf(-v));
                }
                Cout[(size_t)(m0 + ty * 4 + i) * Nc + col] = v;
            }
        }
    }
    if (MODE == 2) {
        __shared__ float Ct[64][65];
#pragma unroll
        for (int j = 0; j < 4; ++j) {
            int col = n0 + tx * 4 + j;
            float bb = bias[col];
            float mu = bnm[col], iv = rsqrtf(bnv[col] + EPSB);
            float gm = bng[col], bt = bnb[col];
#pragma unroll
            for (int i = 0; i < 4; ++i) {
                float v = acc[i][j] + bb;
                v = (v - mu) * iv * gm + bt;
                v = v / (1.f + expf(-v));
                Ct[ty * 4 + i][tx * 4 + j] = v;
            }
        }
        __syncthreads();
#pragma unroll
        for (int it = 0; it < 16; ++it) {
            int r    = it * 4 + (t >> 6);  // output channel within tile
            int colp = t & 63;             // spatial within tile
            Cout[(size_t)(n_img * CC + n0 + r) * HWSZ + p0 + colp] = Ct[colp][r];
        }
    }
}

// Deformable bilinear sampling.
// idx = ((n*HW + p)*G + g)*CG + cg ; value layout (n*HW+p, g*CG+cg) ;
// om layout (n*HW+p, g*27): [ox0,oy0,...,ox8,oy8, m0..m8]
__global__ __launch_bounds__(256) void dcn_sample_k(
    const float* __restrict__ value, const float* __restrict__ om,
    float* __restrict__ acc)
{
    int idx = blockIdx.x * 256 + threadIdx.x;
    int cg = idx & 15;
    int g  = (idx >> 4) & 15;
    int mp = idx >> 8;  // n*HW + p
    int p  = mp % HWSZ;
    int n  = mp / HWSZ;
    int y = p / WW, x = p % WW;
    const float* omr   = om + (size_t)mp * OMC + g * 27;
    const float* vbase = value + (size_t)n * HWSZ * CC + g * CGN + cg;
    float a = 0.f;
#pragma unroll
    for (int k = 0; k < 9; ++k) {
        float ox = omr[2 * k], oy = omr[2 * k + 1], mk = omr[18 + k];
        float py = (float)(y - 1 + k / 3) + oy;
        float px = (float)(x - 1 + k % 3) + ox;
        float fy = floorf(py), fx = floorf(px);
        float wy = py - fy, wx = px - fx;
        int y0 = (int)fy, x0 = (int)fx;
        int y1 = y0 + 1, x1 = x0 + 1;
        float w00 = (1.f - wy) * (1.f - wx), w01 = (1.f - wy) * wx;
        float w10 = wy * (1.f - wx), w11 = wy * wx;
        float s = 0.f;
        if (y0 >= 0 && y0 < HH) {
            const float* row = vbase + (size_t)(y0 * WW) * CC;
            if (x0 >= 0 && x0 < WW) s += w00 * row[(size_t)x0 * CC];
            if (x1 >= 0 && x1 < WW) s += w01 * row[(size_t)x1 * CC];
        }
        if (y1 >= 0 && y1 < HH) {
            const float* row = vbase + (size_t)(y1 * WW) * CC;
            if (x0 >= 0 && x0 < WW) s += w10 * row[(size_t)x0 * CC];
            if (x1 >= 0 && x1 < WW) s += w11 * row[(size_t)x1 * CC];
        }
        a += mk * s;
    }
    acc[(size_t)mp * CC + g * CGN + cg] = a;
}

extern "C" void kernel_launch(void* const* d_in, const int* in_sizes, int n_in,
                              void* d_out, int out_size, void* d_ws, size_t ws_size,
                              hipStream_t stream)
{
    const float* x    = (const float*)d_in[0];
    const float* w1   = (const float*)d_in[1];
    const float* bn1g = (const float*)d_in[2];
    const float* bn1b = (const float*)d_in[3];
    const float* bn1m = (const float*)d_in[4];
    const float* bn1v = (const float*)d_in[5];
    const float* wv   = (const float*)d_in[6];
    const float* bv   = (const float*)d_in[7];
    const float* wom  = (const float*)d_in[8];
    const float* bom  = (const float*)d_in[9];
    const float* wo   = (const float*)d_in[10];
    const float* bo   = (const float*)d_in[11];
    const float* bn2g = (const float*)d_in[12];
    const float* bn2b = (const float*)d_in[13];
    const float* bn2m = (const float*)d_in[14];
    const float* bn2v = (const float*)d_in[15];
    float* out = (float*)d_out;
    float* ws  = (float*)d_ws;

    const int M = NB * HWSZ;  // 12800
    float* h   = ws;                       // M*CC
    float* val = ws + (size_t)M * CC;      // M*CC
    float* om  = val + (size_t)M * CC;     // M*OMC
    float* acc = om + (size_t)M * OMC;     // M*CC

    dim3 blk(256);
    // h = silu(bn1(x @ w1))
    gemm_k<1, true><<<dim3(M / 64, CC / 64), blk, 0, stream>>>(
        x, w1, nullptr, bn1g, bn1b, bn1m, bn1v, h, M, CC, CIN);
    // value = h @ wv + bv
    gemm_k<0, false><<<dim3(M / 64, CC / 64), blk, 0, stream>>>(
        h, wv, bv, nullptr, nullptr, nullptr, nullptr, val, M, CC, CC);
    // om = h @ wom + bom
    gemm_k<0, false><<<dim3(M / 64, (OMC + 63) / 64), blk, 0, stream>>>(
        h, wom, bom, nullptr, nullptr, nullptr, nullptr, om, M, OMC, CC);
    // deformable sampling -> acc
    dcn_sample_k<<<dim3((size_t)M * GG * CGN / 256), blk, 0, stream>>>(val, om, acc);
    // out = transpose(silu(bn2(acc @ wo + bo)))
    gemm_k<2, false><<<dim3(M / 64, CC / 64), blk, 0, stream>>>(
        acc, wo, bo, bn2g, bn2b, bn2m, bn2v, out, M, CC, CC);
}

// Round 2
// 217.430 us; speedup vs baseline: 1.5068x; 1.5068x over previous
//
#include <hip/hip_runtime.h>
#include <hip/hip_bf16.h>
#include <math.h>

typedef __attribute__((ext_vector_type(8))) short bf16x8;
typedef __attribute__((ext_vector_type(4))) float f32x4;

#define NB   2
#define CC   256
#define HH   80
#define WW   80
#define HWSZ 6400
#define MM   (NB * HWSZ)   // 12800
#define NCAT 768           // 256 (value) + 432 (om) + 80 pad
#define EPSB 1e-5f

// ---------------------------------------------------------------------------
// Transpose + fp32->bf16 convert:  out[c][r] = in[r][c], zero-pad c in [Cc,Cpad)
// ---------------------------------------------------------------------------
__global__ __launch_bounds__(256) void transpose_bf16_k(
    const float* __restrict__ in, __hip_bfloat16* __restrict__ outp,
    int R, int Cc, int Cpad, long in_zoff, long out_zoff)
{
    __shared__ float tile[32][33];
    const float* inz = in + (size_t)in_zoff * blockIdx.z;
    __hip_bfloat16* outz = outp + (size_t)out_zoff * blockIdx.z;
    int bc = blockIdx.x * 32, br = blockIdx.y * 32;
    int tx = threadIdx.x & 31, ty = threadIdx.x >> 5;
#pragma unroll
    for (int i = 0; i < 32; i += 8) {
        int r = br + ty + i, c = bc + tx;
        tile[ty + i][tx] = (r < R && c < Cc) ? inz[(size_t)r * Cc + c] : 0.f;
    }
    __syncthreads();
#pragma unroll
    for (int i = 0; i < 32; i += 8) {
        int c = bc + ty + i, r = br + tx;
        if (c < Cpad && r < R)
            outz[(size_t)c * R + r] = __float2bfloat16(tile[tx][ty + i]);
    }
}

// concat bias: [bv(256) | bom(432) | zeros(80)]
__global__ void build_bcat_k(const float* __restrict__ bv,
                             const float* __restrict__ bom,
                             float* __restrict__ bcat)
{
    int t = blockIdx.x * 256 + threadIdx.x;
    if (t >= NCAT) return;
    bcat[t] = (t < 256) ? bv[t] : (t < 688 ? bom[t - 256] : 0.f);
}

// ---------------------------------------------------------------------------
// bf16 MFMA GEMM, m97 structure: 128x128 tile, BK=64, 4 waves (2x2), K=256.
// A: [M][256] bf16 row-major.  Bt: [Npad][256] bf16 (B transposed).
// EPI 0: +bias, store bf16 row-major (ldC)
// EPI 1: BN+SiLU, store bf16 row-major (ldC)
// EPI 2: +bias, BN+SiLU, store fp32 NCHW-transposed
// ---------------------------------------------------------------------------
template <int EPI>
__global__ __launch_bounds__(256) void gemm_mfma(
    const short* __restrict__ A, const short* __restrict__ Bt,
    const float* __restrict__ bias,
    const float* __restrict__ bng, const float* __restrict__ bnb,
    const float* __restrict__ bnm, const float* __restrict__ bnv,
    void* __restrict__ Cout, int ldC)
{
    __shared__ __align__(16) char smem[34048];
    short* As = (short*)smem;            // [128][64]
    short* Bs = (short*)(smem + 16384);  // [128][64]

    const int t = threadIdx.x;
    const int w = t >> 6, l = t & 63;
    const int wr = w >> 1, wc = w & 1;
    const int m0 = blockIdx.x * 128, n0 = blockIdx.y * 128;

    f32x4 acc[4][4] = {};

    for (int k0 = 0; k0 < 256; k0 += 64) {
#pragma unroll
        for (int i = 0; i < 4; ++i) {
            int s = (w << 2) + i;           // 0..15, wave-uniform
            int idx = (s << 6) + l;         // 16B-chunk index, 0..1023
            int row = idx >> 3, ch = idx & 7;
            const short* ga = A + (size_t)(m0 + row) * 256 + k0 + (ch << 3);
            __builtin_amdgcn_global_load_lds(
                (const __attribute__((address_space(1))) void*)ga,
                (__attribute__((address_space(3))) void*)(As + (s << 9)), 16, 0, 0);
            const short* gb = Bt + (size_t)(n0 + row) * 256 + k0 + (ch << 3);
            __builtin_amdgcn_global_load_lds(
                (const __attribute__((address_space(1))) void*)gb,
                (__attribute__((address_space(3))) void*)(Bs + (s << 9)), 16, 0, 0);
        }
        __syncthreads();
#pragma unroll
        for (int kk = 0; kk < 2; ++kk) {
            bf16x8 af[4], bfr[4];
#pragma unroll
            for (int mi = 0; mi < 4; ++mi)
                af[mi] = *(const bf16x8*)(As + (wr * 64 + mi * 16 + (l & 15)) * 64 +
                                          kk * 32 + ((l >> 4) << 3));
#pragma unroll
            for (int ni = 0; ni < 4; ++ni)
                bfr[ni] = *(const bf16x8*)(Bs + (wc * 64 + ni * 16 + (l & 15)) * 64 +
                                           kk * 32 + ((l >> 4) << 3));
#pragma unroll
            for (int mi = 0; mi < 4; ++mi)
#pragma unroll
                for (int ni = 0; ni < 4; ++ni)
                    acc[mi][ni] = __builtin_amdgcn_mfma_f32_16x16x32_bf16(
                        af[mi], bfr[ni], acc[mi][ni], 0, 0, 0);
        }
        __syncthreads();
    }

    // Epilogues. C/D frag mapping: col = l&15, row = (l>>4)*4 + j  [m89]
    if (EPI == 0) {
#pragma unroll
        for (int ni = 0; ni < 4; ++ni) {
            int chn = n0 + wc * 64 + ni * 16 + (l & 15);
            float bb = bias[chn];
#pragma unroll
            for (int mi = 0; mi < 4; ++mi) {
                int mbase = m0 + wr * 64 + mi * 16 + ((l >> 4) << 2);
#pragma unroll
                for (int j = 0; j < 4; ++j) {
                    float v = acc[mi][ni][j] + bb;
                    ((__hip_bfloat16*)Cout)[(size_t)(mbase + j) * ldC + chn] =
                        __float2bfloat16(v);
                }
            }
        }
    } else if (EPI == 1) {
#pragma unroll
        for (int ni = 0; ni < 4; ++ni) {
            int chn = n0 + wc * 64 + ni * 16 + (l & 15);
            float mu = bnm[chn], iv = rsqrtf(bnv[chn] + EPSB);
            float gm = bng[chn], bt = bnb[chn];
#pragma unroll
            for (int mi = 0; mi < 4; ++mi) {
                int mbase = m0 + wr * 64 + mi * 16 + ((l >> 4) << 2);
#pragma unroll
                for (int j = 0; j < 4; ++j) {
                    float v = acc[mi][ni][j];
                    v = (v - mu) * iv * gm + bt;
                    v = v / (1.f + __expf(-v));
                    ((__hip_bfloat16*)Cout)[(size_t)(mbase + j) * ldC + chn] =
                        __float2bfloat16(v);
                }
            }
        }
    } else {
        // EPI 2: LDS-transposed NCHW fp32 store with bias + BN2 + SiLU
        float(*CtT)[132] = (float(*)[132])smem;  // [64 ch][128 m] (+pad)
        const int nimg = m0 / HWSZ;              // 6400 % 128 == 0
        const int p0 = m0 % HWSZ;
#pragma unroll
        for (int h2 = 0; h2 < 2; ++h2) {
            if (wc == h2) {
#pragma unroll
                for (int ni = 0; ni < 4; ++ni)
#pragma unroll
                    for (int mi = 0; mi < 4; ++mi)
#pragma unroll
                        for (int j = 0; j < 4; ++j)
                            CtT[ni * 16 + (l & 15)]
                               [wr * 64 + mi * 16 + ((l >> 4) << 2) + j] =
                                   acc[mi][ni][j];
            }
            __syncthreads();
#pragma unroll
            for (int it = 0; it < 8; ++it) {
                int e4 = it * 256 + t;   // float4 idx over [64][128]
                int row = e4 >> 5;       // ch_local
                int c4 = e4 & 31;
                int chn = n0 + h2 * 64 + row;
                float bb = bias[chn];
                float mu = bnm[chn], iv = rsqrtf(bnv[chn] + EPSB);
                float gm = bng[chn], bt = bnb[chn];
                f32x4 v = *(f32x4*)&CtT[row][c4 * 4];
#pragma unroll
                for (int j = 0; j < 4; ++j) {
                    float u = v[j] + bb;
                    u = (u - mu) * iv * gm + bt;
                    u = u / (1.f + __expf(-u));
                    v[j] = u;
                }
                *(f32x4*)&((float*)Cout)[(size_t)(nimg * CC + chn) * HWSZ + p0 + c4 * 4] = v;
            }
            __syncthreads();
        }
    }
}

// ---------------------------------------------------------------------------
// Deformable bilinear sampling, bf16 in/out, fp32 math.
// C2: [M][768] = [value(256) | om(432) | pad(80)]
// ---------------------------------------------------------------------------
__global__ __launch_bounds__(256) void dcn_sample_k(
    const __hip_bfloat16* __restrict__ C2, __hip_bfloat16* __restrict__ accb)
{
    int idx = blockIdx.x * 256 + threadIdx.x;
    int cg = idx & 15;
    int g = (idx >> 4) & 15;
    int mp = idx >> 8;  // n*HW + p
    int p = mp % HWSZ;
    int n = mp / HWSZ;
    int y = p / WW, x = p % WW;
    const __hip_bfloat16* omr = C2 + (size_t)mp * NCAT + 256 + g * 27;
    const __hip_bfloat16* vb = C2 + (size_t)n * HWSZ * NCAT + g * 16 + cg;
    float a = 0.f;
#pragma unroll
    for (int k = 0; k < 9; ++k) {
        float ox = __bfloat162float(omr[2 * k]);
        float oy = __bfloat162float(omr[2 * k + 1]);
        float mk = __bfloat162float(omr[18 + k]);
        float py = (float)(y - 1 + k / 3) + oy;
        float px = (float)(x - 1 + k % 3) + ox;
        float fy = floorf(py), fx = floorf(px);
        float wy = py - fy, wx = px - fx;
        int y0 = (int)fy, x0 = (int)fx;
        int y1 = y0 + 1, x1 = x0 + 1;
        float w00 = (1.f - wy) * (1.f - wx), w01 = (1.f - wy) * wx;
        float w10 = wy * (1.f - wx), w11 = wy * wx;
        float s = 0.f;
        if (y0 >= 0 && y0 < HH) {
            const __hip_bfloat16* row = vb + (size_t)(y0 * WW) * NCAT;
            if (x0 >= 0 && x0 < WW) s += w00 * __bfloat162float(row[(size_t)x0 * NCAT]);
            if (x1 >= 0 && x1 < WW) s += w01 * __bfloat162float(row[(size_t)x1 * NCAT]);
        }
        if (y1 >= 0 && y1 < HH) {
            const __hip_bfloat16* row = vb + (size_t)(y1 * WW) * NCAT;
            if (x0 >= 0 && x0 < WW) s += w10 * __bfloat162float(row[(size_t)x0 * NCAT]);
            if (x1 >= 0 && x1 < WW) s += w11 * __bfloat162float(row[(size_t)x1 * NCAT]);
        }
        a += mk * s;
    }
    accb[(size_t)mp * CC + g * 16 + cg] = __float2bfloat16(a);
}

// ---------------------------------------------------------------------------
extern "C" void kernel_launch(void* const* d_in, const int* in_sizes, int n_in,
                              void* d_out, int out_size, void* d_ws, size_t ws_size,
                              hipStream_t stream)
{
    const float* x    = (const float*)d_in[0];
    const float* w1   = (const float*)d_in[1];
    const float* bn1g = (const float*)d_in[2];
    const float* bn1b = (const float*)d_in[3];
    const float* bn1m = (const float*)d_in[4];
    const float* bn1v = (const float*)d_in[5];
    const float* wv   = (const float*)d_in[6];
    const float* bv   = (const float*)d_in[7];
    const float* wom  = (const float*)d_in[8];
    const float* bom  = (const float*)d_in[9];
    const float* wo   = (const float*)d_in[10];
    const float* bo   = (const float*)d_in[11];
    const float* bn2g = (const float*)d_in[12];
    const float* bn2b = (const float*)d_in[13];
    const float* bn2m = (const float*)d_in[14];
    const float* bn2v = (const float*)d_in[15];
    float* out = (float*)d_out;

    char* w = (char*)d_ws;
    __hip_bfloat16* xT    = (__hip_bfloat16*)(w);                 // [M][256]
    __hip_bfloat16* hbuf  = (__hip_bfloat16*)(w + 6553600);       // [M][256]
    __hip_bfloat16* C2    = (__hip_bfloat16*)(w + 13107200);      // [M][768]
    __hip_bfloat16* accb  = (__hip_bfloat16*)(w + 32768000);      // [M][256]
    __hip_bfloat16* w1T   = (__hip_bfloat16*)(w + 39321600);      // [256][256]
    __hip_bfloat16* woT   = (__hip_bfloat16*)(w + 39452672);      // [256][256]
    __hip_bfloat16* BcatT = (__hip_bfloat16*)(w + 39583744);      // [768][256]
    float*          bcat  = (float*)(w + 39976960);               // [768]

    dim3 blk(256);

    // weight / input reformatting (bf16, transposed)
    transpose_bf16_k<<<dim3(8, 8, 1), blk, 0, stream>>>(w1, w1T, 256, 256, 256, 0, 0);
    transpose_bf16_k<<<dim3(8, 8, 1), blk, 0, stream>>>(wv, BcatT, 256, 256, 256, 0, 0);
    transpose_bf16_k<<<dim3(16, 8, 1), blk, 0, stream>>>(wom, BcatT + 256 * 256, 256, 432, 512, 0, 0);
    transpose_bf16_k<<<dim3(8, 8, 1), blk, 0, stream>>>(wo, woT, 256, 256, 256, 0, 0);
    build_bcat_k<<<dim3(3), blk, 0, stream>>>(bv, bom, bcat);
    // x NCHW -> xT [n*HW+p][c]
    transpose_bf16_k<<<dim3(200, 8, 2), blk, 0, stream>>>(
        x, xT, 256, 6400, 6400, (long)256 * 6400, (long)6400 * 256);

    // h = silu(bn1(x @ w1))
    gemm_mfma<1><<<dim3(100, 2), blk, 0, stream>>>(
        (const short*)xT, (const short*)w1T, nullptr,
        bn1g, bn1b, bn1m, bn1v, hbuf, CC);
    // C2 = h @ [wv|wom] + bcat
    gemm_mfma<0><<<dim3(100, 6), blk, 0, stream>>>(
        (const short*)hbuf, (const short*)BcatT, bcat,
        nullptr, nullptr, nullptr, nullptr, C2, NCAT);
    // deformable sampling -> accb
    dcn_sample_k<<<dim3(MM * 256 / 256), blk, 0, stream>>>(C2, accb);
    // out = NCHW(silu(bn2(accb @ wo + bo)))
    gemm_mfma<2><<<dim3(100, 2), blk, 0, stream>>>(
        (const short*)accb, (const short*)woT, bo,
        bn2g, bn2b, bn2m, bn2v, out, 0);
}

// Round 8
// 151.394 us; speedup vs baseline: 2.1641x; 1.4362x over previous
//
#include <hip/hip_runtime.h>
#include <hip/hip_bf16.h>
#include <math.h>

typedef __attribute__((ext_vector_type(8))) short bf16x8;
typedef __attribute__((ext_vector_type(4))) float f32x4;

#define NB   2
#define CC   256
#define HH   80
#define WW   80
#define HWSZ 6400
#define MM   (NB * HWSZ)   // 12800
#define NCAT 768           // 256 (value) | 512 (om: 16 groups x (27 used + 5 pad))
#define EPSB 1e-5f

// ---------------------------------------------------------------------------
// x NCHW -> xT [n*HW+p][c] bf16 (32x32 LDS tile transpose)
// ---------------------------------------------------------------------------
__global__ __launch_bounds__(256) void transpose_x_k(
    const float* __restrict__ in, __hip_bfloat16* __restrict__ outp)
{
    __shared__ float tile[32][33];
    const float* inz = in + (size_t)256 * HWSZ * blockIdx.z;
    __hip_bfloat16* outz = outp + (size_t)HWSZ * 256 * blockIdx.z;
    int bc = blockIdx.x * 32, br = blockIdx.y * 32;  // bc: spatial, br: channel
    int tx = threadIdx.x & 31, ty = threadIdx.x >> 5;
#pragma unroll
    for (int i = 0; i < 32; i += 8)
        tile[ty + i][tx] = inz[(size_t)(br + ty + i) * HWSZ + bc + tx];
    __syncthreads();
#pragma unroll
    for (int i = 0; i < 32; i += 8)
        outz[(size_t)(bc + ty + i) * 256 + br + tx] =
            __float2bfloat16(tile[tx][ty + i]);
}

// ---------------------------------------------------------------------------
// One-launch weight prep:
//   b   0.. 63 : w1T[d][c]   = w1[c][d]
//   b  64..127 : BcatT[n][c] = wv[c][n]               (rows 0..255)
//   b 128..191 : woT[d][c]   = wo[c][d]
//   b 192..319 : BcatT[256+g*32+jj][c] = jj<27 ? wom[c][g*27+jj] : 0
//   b 320      : bcat[768] = [bv | om-bias remapped]
// ---------------------------------------------------------------------------
__device__ inline void t32g(const float* __restrict__ in, int inld, int scol0,
                            int ncols, __hip_bfloat16* __restrict__ out,
                            int orow0, int r0, int tid)
{
    __shared__ float tile[32][33];
    int tx = tid & 31, ty = tid >> 5;
#pragma unroll
    for (int i = 0; i < 32; i += 8)
        tile[ty + i][tx] = (tx < ncols)
            ? in[(size_t)(r0 + ty + i) * inld + scol0 + tx] : 0.f;
    __syncthreads();
#pragma unroll
    for (int i = 0; i < 32; i += 8)
        out[(size_t)(orow0 + ty + i) * 256 + r0 + tx] =
            __float2bfloat16(tile[tx][ty + i]);
}

__global__ __launch_bounds__(256) void prep_weights_k(
    const float* __restrict__ w1, const float* __restrict__ wv,
    const float* __restrict__ wom, const float* __restrict__ wo,
    const float* __restrict__ bv, const float* __restrict__ bom,
    __hip_bfloat16* __restrict__ w1T, __hip_bfloat16* __restrict__ BcatT,
    __hip_bfloat16* __restrict__ woT, float* __restrict__ bcat)
{
    int b = blockIdx.x, t = threadIdx.x;
    if (b < 64) {
        t32g(w1, 256, (b >> 3) * 32, 32, w1T, (b >> 3) * 32, (b & 7) * 32, t);
    } else if (b < 128) {
        int b2 = b - 64;
        t32g(wv, 256, (b2 >> 3) * 32, 32, BcatT, (b2 >> 3) * 32, (b2 & 7) * 32, t);
    } else if (b < 192) {
        int b2 = b - 128;
        t32g(wo, 256, (b2 >> 3) * 32, 32, woT, (b2 >> 3) * 32, (b2 & 7) * 32, t);
    } else if (b < 320) {
        int b2 = b - 192;
        int g = b2 >> 3, ct = b2 & 7;
        t32g(wom, 432, g * 27, 27, BcatT + 256 * 256, g * 32, ct * 32, t);
    } else {
        bcat[t] = bv[t];
#pragma unroll
        for (int j = 0; j < 2; ++j) {
            int r = j * 256 + t;         // om row index, 0..511
            int g = r >> 5, jj = r & 31;
            bcat[256 + r] = (jj < 27) ? bom[g * 27 + jj] : 0.f;
        }
    }
}

// ---------------------------------------------------------------------------
// bf16 MFMA GEMM, m97 structure: 128x128 tile, BK=64, 4 waves (2x2), K=256.
// ---------------------------------------------------------------------------
template <int EPI>
__global__ __launch_bounds__(256) void gemm_mfma(
    const short* __restrict__ A, const short* __restrict__ Bt,
    const float* __restrict__ bias,
    const float* __restrict__ bng, const float* __restrict__ bnb,
    const float* __restrict__ bnm, const float* __restrict__ bnv,
    void* __restrict__ Cout, int ldC)
{
    __shared__ __align__(16) char smem[34048];
    short* As = (short*)smem;            // [128][64]
    short* Bs = (short*)(smem + 16384);  // [128][64]

    const int t = threadIdx.x;
    const int w = t >> 6, l = t & 63;
    const int wr = w >> 1, wc = w & 1;
    const int m0 = blockIdx.x * 128, n0 = blockIdx.y * 128;

    f32x4 acc[4][4] = {};

    for (int k0 = 0; k0 < 256; k0 += 64) {
#pragma unroll
        for (int i = 0; i < 4; ++i) {
            int s = (w << 2) + i;           // 0..15, wave-uniform
            int idx = (s << 6) + l;         // 16B-chunk index
            int row = idx >> 3, ch = idx & 7;
            const short* ga = A + (size_t)(m0 + row) * 256 + k0 + (ch << 3);
            __builtin_amdgcn_global_load_lds(
                (const __attribute__((address_space(1))) void*)ga,
                (__attribute__((address_space(3))) void*)(As + (s << 9)), 16, 0, 0);
            const short* gb = Bt + (size_t)(n0 + row) * 256 + k0 + (ch << 3);
            __builtin_amdgcn_global_load_lds(
                (const __attribute__((address_space(1))) void*)gb,
                (__attribute__((address_space(3))) void*)(Bs + (s << 9)), 16, 0, 0);
        }
        __syncthreads();
#pragma unroll
        for (int kk = 0; kk < 2; ++kk) {
            bf16x8 af[4], bfr[4];
#pragma unroll
            for (int mi = 0; mi < 4; ++mi)
                af[mi] = *(const bf16x8*)(As + (wr * 64 + mi * 16 + (l & 15)) * 64 +
                                          kk * 32 + ((l >> 4) << 3));
#pragma unroll
            for (int ni = 0; ni < 4; ++ni)
                bfr[ni] = *(const bf16x8*)(Bs + (wc * 64 + ni * 16 + (l & 15)) * 64 +
                                           kk * 32 + ((l >> 4) << 3));
#pragma unroll
            for (int mi = 0; mi < 4; ++mi)
#pragma unroll
                for (int ni = 0; ni < 4; ++ni)
                    acc[mi][ni] = __builtin_amdgcn_mfma_f32_16x16x32_bf16(
                        af[mi], bfr[ni], acc[mi][ni], 0, 0, 0);
        }
        __syncthreads();
    }

    if (EPI == 0) {
#pragma unroll
        for (int ni = 0; ni < 4; ++ni) {
            int chn = n0 + wc * 64 + ni * 16 + (l & 15);
            float bb = bias[chn];
#pragma unroll
            for (int mi = 0; mi < 4; ++mi) {
                int mbase = m0 + wr * 64 + mi * 16 + ((l >> 4) << 2);
#pragma unroll
                for (int j = 0; j < 4; ++j) {
                    float v = acc[mi][ni][j] + bb;
                    ((__hip_bfloat16*)Cout)[(size_t)(mbase + j) * ldC + chn] =
                        __float2bfloat16(v);
                }
            }
        }
    } else if (EPI == 1) {
#pragma unroll
        for (int ni = 0; ni < 4; ++ni) {
            int chn = n0 + wc * 64 + ni * 16 + (l & 15);
            float mu = bnm[chn], iv = rsqrtf(bnv[chn] + EPSB);
            float gm = bng[chn], bt = bnb[chn];
#pragma unroll
            for (int mi = 0; mi < 4; ++mi) {
                int mbase = m0 + wr * 64 + mi * 16 + ((l >> 4) << 2);
#pragma unroll
                for (int j = 0; j < 4; ++j) {
                    float v = acc[mi][ni][j];
                    v = (v - mu) * iv * gm + bt;
                    v = v / (1.f + __expf(-v));
                    ((__hip_bfloat16*)Cout)[(size_t)(mbase + j) * ldC + chn] =
                        __float2bfloat16(v);
                }
            }
        }
    } else {
        // EPI 2: LDS-transposed NCHW fp32 store with bias + BN2 + SiLU
        float(*CtT)[132] = (float(*)[132])smem;  // [64 ch][128 m] (+pad)
        const int nimg = m0 / HWSZ;              // 6400 % 128 == 0
        const int p0 = m0 % HWSZ;
#pragma unroll
        for (int h2 = 0; h2 < 2; ++h2) {
            if (wc == h2) {
#pragma unroll
                for (int ni = 0; ni < 4; ++ni)
#pragma unroll
                    for (int mi = 0; mi < 4; ++mi)
#pragma unroll
                        for (int j = 0; j < 4; ++j)
                            CtT[ni * 16 + (l & 15)]
                               [wr * 64 + mi * 16 + ((l >> 4) << 2) + j] =
                                   acc[mi][ni][j];
            }
            __syncthreads();
#pragma unroll
            for (int it = 0; it < 8; ++it) {
                int e4 = it * 256 + t;
                int row = e4 >> 5;
                int c4 = e4 & 31;
                int chn = n0 + h2 * 64 + row;
                float bb = bias[chn];
                float mu = bnm[chn], iv = rsqrtf(bnv[chn] + EPSB);
                float gm = bng[chn], bt = bnb[chn];
                f32x4 v = *(f32x4*)&CtT[row][c4 * 4];
#pragma unroll
                for (int j = 0; j < 4; ++j) {
                    float u = v[j] + bb;
                    u = (u - mu) * iv * gm + bt;
                    u = u / (1.f + __expf(-u));
                    v[j] = u;
                }
                *(f32x4*)&((float*)Cout)[(size_t)(nimg * CC + chn) * HWSZ + p0 + c4 * 4] = v;
            }
            __syncthreads();
        }
    }
}

// ---------------------------------------------------------------------------
// Deformable bilinear sampling: 8 channels/thread, bf16x8 gathers, fp32 math.
// C2 row: [value(256) | om: g*32 + {ox,oy pairs(18), m(9), pad(5)}]
// Thread map: half = idx&1 (8-ch half), g = (idx>>1)&15, mp = idx>>5.
// ---------------------------------------------------------------------------
__device__ inline void fma8(float* acc, const __hip_bfloat16* ptr, float wgt)
{
    bf16x8 v = *(const bf16x8*)ptr;
#pragma unroll
    for (int j = 0; j < 8; ++j) {
        union { unsigned u; float f; } cv;
        cv.u = ((unsigned)(unsigned short)v[j]) << 16;
        acc[j] = fmaf(wgt, cv.f, acc[j]);
    }
}

__global__ __launch_bounds__(256) void dcn_sample_k(
    const __hip_bfloat16* __restrict__ C2, __hip_bfloat16* __restrict__ accb)
{
    const int idx = blockIdx.x * 256 + threadIdx.x;
    const int half = idx & 1;
    const int g = (idx >> 1) & 15;
    const int mp = idx >> 5;
    const int p = mp % HWSZ;
    const int n = mp / HWSZ;
    const int y = p / WW, x = p % WW;

    const unsigned* omw =
        (const unsigned*)(C2 + (size_t)mp * NCAT + 256 + g * 32);
    const __hip_bfloat16* vb =
        C2 + (size_t)n * HWSZ * NCAT + g * 16 + half * 8;

    // masks: bytes 36..55 -> u32 words 9..13
    float mk[9];
    {
        unsigned mw[5];
#pragma unroll
        for (int i = 0; i < 5; ++i) mw[i] = omw[9 + i];
#pragma unroll
        for (int i = 0; i < 9; ++i) {
            unsigned w16 = (i & 1) ? (mw[i >> 1] >> 16) : (mw[i >> 1] & 0xffffu);
            union { unsigned u; float f; } cv; cv.u = w16 << 16;
            mk[i] = cv.f;
        }
    }

    float acc[8] = {};
#pragma unroll
    for (int k = 0; k < 9; ++k) {
        unsigned ow = omw[k];
        union { unsigned u; float f; } cx, cy;
        cx.u = (ow & 0xffffu) << 16;   // ox
        cy.u = ow & 0xffff0000u;       // oy
        float px = (float)(x - 1 + (k % 3)) + cx.f;
        float py = (float)(y - 1 + (k / 3)) + cy.f;
        float fx = floorf(px), fy = floorf(py);
        float wx = px - fx, wy = py - fy;
        int x0 = (int)fx, y0 = (int)fy;
        int x1 = x0 + 1, y1 = y0 + 1;
        float ax0 = ((unsigned)x0 < (unsigned)WW) ? (1.f - wx) : 0.f;
        float ax1 = ((unsigned)x1 < (unsigned)WW) ? wx : 0.f;
        float ay0 = ((unsigned)y0 < (unsigned)HH) ? mk[k] * (1.f - wy) : 0.f;
        float ay1 = ((unsigned)y1 < (unsigned)HH) ? mk[k] * wy : 0.f;
        int xc0 = min(max(x0, 0), WW - 1);
        int xc1 = min(max(x1, 0), WW - 1);
        int yc0 = min(max(y0, 0), HH - 1);
        int yc1 = min(max(y1, 0), HH - 1);
        const __hip_bfloat16* r0 = vb + (size_t)(yc0 * WW) * NCAT;
        const __hip_bfloat16* r1 = vb + (size_t)(yc1 * WW) * NCAT;
        fma8(acc, r0 + (size_t)xc0 * NCAT, ay0 * ax0);
        fma8(acc, r0 + (size_t)xc1 * NCAT, ay0 * ax1);
        fma8(acc, r1 + (size_t)xc0 * NCAT, ay1 * ax0);
        fma8(acc, r1 + (size_t)xc1 * NCAT, ay1 * ax1);
    }

    __hip_bfloat16* op = accb + (size_t)mp * CC + g * 16 + half * 8;
    bf16x8 ov;
#pragma unroll
    for (int j = 0; j < 8; ++j) {
        __hip_bfloat16 b = __float2bfloat16(acc[j]);
        ov[j] = *reinterpret_cast<short*>(&b);
    }
    *(bf16x8*)op = ov;
}

// ---------------------------------------------------------------------------
extern "C" void kernel_launch(void* const* d_in, const int* in_sizes, int n_in,
                              void* d_out, int out_size, void* d_ws, size_t ws_size,
                              hipStream_t stream)
{
    const float* x    = (const float*)d_in[0];
    const float* w1   = (const float*)d_in[1];
    const float* bn1g = (const float*)d_in[2];
    const float* bn1b = (const float*)d_in[3];
    const float* bn1m = (const float*)d_in[4];
    const float* bn1v = (const float*)d_in[5];
    const float* wv   = (const float*)d_in[6];
    const float* bv   = (const float*)d_in[7];
    const float* wom  = (const float*)d_in[8];
    const float* bom  = (const float*)d_in[9];
    const float* wo   = (const float*)d_in[10];
    const float* bo   = (const float*)d_in[11];
    const float* bn2g = (const float*)d_in[12];
    const float* bn2b = (const float*)d_in[13];
    const float* bn2m = (const float*)d_in[14];
    const float* bn2v = (const float*)d_in[15];
    float* out = (float*)d_out;

    char* w = (char*)d_ws;
    __hip_bfloat16* xT    = (__hip_bfloat16*)(w);                 // [M][256]
    __hip_bfloat16* hbuf  = (__hip_bfloat16*)(w + 6553600);       // [M][256]
    __hip_bfloat16* C2    = (__hip_bfloat16*)(w + 13107200);      // [M][768]
    __hip_bfloat16* accb  = (__hip_bfloat16*)(w + 32768000);      // [M][256]
    __hip_bfloat16* w1T   = (__hip_bfloat16*)(w + 39321600);      // [256][256]
    __hip_bfloat16* woT   = (__hip_bfloat16*)(w + 39452672);      // [256][256]
    __hip_bfloat16* BcatT = (__hip_bfloat16*)(w + 39583744);      // [768][256]
    float*          bcat  = (float*)(w + 39976960);               // [768]

    dim3 blk(256);

    prep_weights_k<<<dim3(321), blk, 0, stream>>>(
        w1, wv, wom, wo, bv, bom, w1T, BcatT, woT, bcat);
    transpose_x_k<<<dim3(200, 8, 2), blk, 0, stream>>>(x, xT);

    // h = silu(bn1(x @ w1))
    gemm_mfma<1><<<dim3(100, 2), blk, 0, stream>>>(
        (const short*)xT, (const short*)w1T, nullptr,
        bn1g, bn1b, bn1m, bn1v, hbuf, CC);
    // C2 = h @ [wv|wom'] + bcat
    gemm_mfma<0><<<dim3(100, 6), blk, 0, stream>>>(
        (const short*)hbuf, (const short*)BcatT, bcat,
        nullptr, nullptr, nullptr, nullptr, C2, NCAT);
    // deformable sampling -> accb
    dcn_sample_k<<<dim3(MM * 32 / 256), blk, 0, stream>>>(C2, accb);
    // out = NCHW(silu(bn2(accb @ wo + bo)))
    gemm_mfma<2><<<dim3(100, 2), blk, 0, stream>>>(
        (const short*)accb, (const short*)woT, bo,
        bn2g, bn2b, bn2m, bn2v, out, 0);
}

// Round 9
// 150.608 us; speedup vs baseline: 2.1754x; 1.0052x over previous
//
#include <hip/hip_runtime.h>
#include <hip/hip_bf16.h>
#include <math.h>

typedef __attribute__((ext_vector_type(8))) short bf16x8;
typedef __attribute__((ext_vector_type(4))) float f32x4;

#define NB   2
#define CC   256
#define HH   80
#define WW   80
#define HWSZ 6400
#define MM   (NB * HWSZ)   // 12800
#define NCAT 768           // 256 (value) | 512 (om: 16 groups x (27 used + 5 pad))
#define EPSB 1e-5f

// ---------------------------------------------------------------------------
// x NCHW -> xT [n*HW+p][c] bf16 (32x32 LDS tile transpose)
// ---------------------------------------------------------------------------
__global__ __launch_bounds__(256) void transpose_x_k(
    const float* __restrict__ in, __hip_bfloat16* __restrict__ outp)
{
    __shared__ float tile[32][33];
    const float* inz = in + (size_t)256 * HWSZ * blockIdx.z;
    __hip_bfloat16* outz = outp + (size_t)HWSZ * 256 * blockIdx.z;
    int bc = blockIdx.x * 32, br = blockIdx.y * 32;  // bc: spatial, br: channel
    int tx = threadIdx.x & 31, ty = threadIdx.x >> 5;
#pragma unroll
    for (int i = 0; i < 32; i += 8)
        tile[ty + i][tx] = inz[(size_t)(br + ty + i) * HWSZ + bc + tx];
    __syncthreads();
#pragma unroll
    for (int i = 0; i < 32; i += 8)
        outz[(size_t)(bc + ty + i) * 256 + br + tx] =
            __float2bfloat16(tile[tx][ty + i]);
}

// ---------------------------------------------------------------------------
// One-launch weight prep (unchanged from round 8, verified)
// ---------------------------------------------------------------------------
__device__ inline void t32g(const float* __restrict__ in, int inld, int scol0,
                            int ncols, __hip_bfloat16* __restrict__ out,
                            int orow0, int r0, int tid)
{
    __shared__ float tile[32][33];
    int tx = tid & 31, ty = tid >> 5;
#pragma unroll
    for (int i = 0; i < 32; i += 8)
        tile[ty + i][tx] = (tx < ncols)
            ? in[(size_t)(r0 + ty + i) * inld + scol0 + tx] : 0.f;
    __syncthreads();
#pragma unroll
    for (int i = 0; i < 32; i += 8)
        out[(size_t)(orow0 + ty + i) * 256 + r0 + tx] =
            __float2bfloat16(tile[tx][ty + i]);
}

__global__ __launch_bounds__(256) void prep_weights_k(
    const float* __restrict__ w1, const float* __restrict__ wv,
    const float* __restrict__ wom, const float* __restrict__ wo,
    const float* __restrict__ bv, const float* __restrict__ bom,
    __hip_bfloat16* __restrict__ w1T, __hip_bfloat16* __restrict__ BcatT,
    __hip_bfloat16* __restrict__ woT, float* __restrict__ bcat)
{
    int b = blockIdx.x, t = threadIdx.x;
    if (b < 64) {
        t32g(w1, 256, (b >> 3) * 32, 32, w1T, (b >> 3) * 32, (b & 7) * 32, t);
    } else if (b < 128) {
        int b2 = b - 64;
        t32g(wv, 256, (b2 >> 3) * 32, 32, BcatT, (b2 >> 3) * 32, (b2 & 7) * 32, t);
    } else if (b < 192) {
        int b2 = b - 128;
        t32g(wo, 256, (b2 >> 3) * 32, 32, woT, (b2 >> 3) * 32, (b2 & 7) * 32, t);
    } else if (b < 320) {
        int b2 = b - 192;
        int g = b2 >> 3, ct = b2 & 7;
        t32g(wom, 432, g * 27, 27, BcatT + 256 * 256, g * 32, ct * 32, t);
    } else {
        bcat[t] = bv[t];
#pragma unroll
        for (int j = 0; j < 2; ++j) {
            int r = j * 256 + t;         // om row index, 0..511
            int g = r >> 5, jj = r & 31;
            bcat[256 + r] = (jj < 27) ? bom[g * 27 + jj] : 0.f;
        }
    }
}

// ---------------------------------------------------------------------------
// bf16 MFMA GEMM: 64x128 tile, BK=64, 4 waves (2x2), K=256, 2-phase
// double-buffered prefetch (STAGE(t+1) issued before COMPUTE(t); one
// barrier per K-step drains next-tile loads AFTER compute has overlapped).
// ---------------------------------------------------------------------------
template <int EPI>
__global__ __launch_bounds__(256) void gemm_mfma(
    const short* __restrict__ A, const short* __restrict__ Bt,
    const float* __restrict__ bias,
    const float* __restrict__ bng, const float* __restrict__ bnb,
    const float* __restrict__ bnm, const float* __restrict__ bnv,
    void* __restrict__ Cout, int ldC)
{
    __shared__ __align__(16) char smem[49152];
    short* As = (short*)smem;            // [2][64*64]
    short* Bs = (short*)(smem + 16384);  // [2][128*64]

    const int t = threadIdx.x;
    const int w = t >> 6, l = t & 63;
    const int wr = w >> 1, wc = w & 1;
    const int m0 = blockIdx.x * 64, n0 = blockIdx.y * 128;

    f32x4 acc[2][4] = {};

    auto STAGE = [&](int b, int k0) {
        short* AsB = As + b * 4096;
        short* BsB = Bs + b * 8192;
#pragma unroll
        for (int i = 0; i < 2; ++i) {
            int s = (w << 1) + i;          // 0..7
            int c = (s << 6) + l;          // A chunk 0..511
            int row = c >> 3, ch = c & 7;
            const short* ga = A + (size_t)(m0 + row) * 256 + k0 + (ch << 3);
            __builtin_amdgcn_global_load_lds(
                (const __attribute__((address_space(1))) void*)ga,
                (__attribute__((address_space(3))) void*)(AsB + (s << 9)), 16, 0, 0);
        }
#pragma unroll
        for (int i = 0; i < 4; ++i) {
            int s = (w << 2) + i;          // 0..15
            int c = (s << 6) + l;          // B chunk 0..1023
            int row = c >> 3, ch = c & 7;
            const short* gb = Bt + (size_t)(n0 + row) * 256 + k0 + (ch << 3);
            __builtin_amdgcn_global_load_lds(
                (const __attribute__((address_space(1))) void*)gb,
                (__attribute__((address_space(3))) void*)(BsB + (s << 9)), 16, 0, 0);
        }
    };

    auto COMPUTE = [&](int b) {
        const short* AsB = As + b * 4096;
        const short* BsB = Bs + b * 8192;
#pragma unroll
        for (int kk = 0; kk < 2; ++kk) {
            bf16x8 af[2], bfr[4];
#pragma unroll
            for (int mi = 0; mi < 2; ++mi)
                af[mi] = *(const bf16x8*)(AsB + (wr * 32 + mi * 16 + (l & 15)) * 64 +
                                          kk * 32 + ((l >> 4) << 3));
#pragma unroll
            for (int ni = 0; ni < 4; ++ni)
                bfr[ni] = *(const bf16x8*)(BsB + (wc * 64 + ni * 16 + (l & 15)) * 64 +
                                           kk * 32 + ((l >> 4) << 3));
#pragma unroll
            for (int mi = 0; mi < 2; ++mi)
#pragma unroll
                for (int ni = 0; ni < 4; ++ni)
                    acc[mi][ni] = __builtin_amdgcn_mfma_f32_16x16x32_bf16(
                        af[mi], bfr[ni], acc[mi][ni], 0, 0, 0);
        }
    };

    STAGE(0, 0);
    __syncthreads();
#pragma unroll
    for (int tt = 0; tt < 4; ++tt) {
        if (tt < 3) STAGE((tt + 1) & 1, (tt + 1) * 64);
        COMPUTE(tt & 1);
        __syncthreads();
    }

    if (EPI == 0) {
#pragma unroll
        for (int ni = 0; ni < 4; ++ni) {
            int chn = n0 + wc * 64 + ni * 16 + (l & 15);
            float bb = bias[chn];
#pragma unroll
            for (int mi = 0; mi < 2; ++mi) {
                int mbase = m0 + wr * 32 + mi * 16 + ((l >> 4) << 2);
#pragma unroll
                for (int j = 0; j < 4; ++j) {
                    float v = acc[mi][ni][j] + bb;
                    ((__hip_bfloat16*)Cout)[(size_t)(mbase + j) * ldC + chn] =
                        __float2bfloat16(v);
                }
            }
        }
    } else if (EPI == 1) {
#pragma unroll
        for (int ni = 0; ni < 4; ++ni) {
            int chn = n0 + wc * 64 + ni * 16 + (l & 15);
            float mu = bnm[chn], iv = rsqrtf(bnv[chn] + EPSB);
            float gm = bng[chn], bt = bnb[chn];
#pragma unroll
            for (int mi = 0; mi < 2; ++mi) {
                int mbase = m0 + wr * 32 + mi * 16 + ((l >> 4) << 2);
#pragma unroll
                for (int j = 0; j < 4; ++j) {
                    float v = acc[mi][ni][j];
                    v = (v - mu) * iv * gm + bt;
                    v = v / (1.f + __expf(-v));
                    ((__hip_bfloat16*)Cout)[(size_t)(mbase + j) * ldC + chn] =
                        __float2bfloat16(v);
                }
            }
        }
    } else {
        // EPI 2: LDS-transposed NCHW fp32 store with bias + BN2 + SiLU
        float(*CtT)[68] = (float(*)[68])smem;    // [64 ch][64 m] (+4 pad)
        const int nimg = m0 / HWSZ;              // 6400 % 64 == 0
        const int p0 = m0 % HWSZ;
#pragma unroll
        for (int h2 = 0; h2 < 2; ++h2) {
            if (wc == h2) {
#pragma unroll
                for (int ni = 0; ni < 4; ++ni)
#pragma unroll
                    for (int mi = 0; mi < 2; ++mi)
#pragma unroll
                        for (int j = 0; j < 4; ++j)
                            CtT[ni * 16 + (l & 15)]
                               [wr * 32 + mi * 16 + ((l >> 4) << 2) + j] =
                                   acc[mi][ni][j];
            }
            __syncthreads();
#pragma unroll
            for (int it = 0; it < 4; ++it) {
                int e4 = it * 256 + t;   // f32x4 idx over [64][16]
                int row = e4 >> 4;       // ch_local
                int c4 = e4 & 15;
                int chn = n0 + h2 * 64 + row;
                float bb = bias[chn];
                float mu = bnm[chn], iv = rsqrtf(bnv[chn] + EPSB);
                float gm = bng[chn], bt = bnb[chn];
                f32x4 v = *(f32x4*)&CtT[row][c4 * 4];
#pragma unroll
                for (int j = 0; j < 4; ++j) {
                    float u = v[j] + bb;
                    u = (u - mu) * iv * gm + bt;
                    u = u / (1.f + __expf(-u));
                    v[j] = u;
                }
                *(f32x4*)&((float*)Cout)[(size_t)(nimg * CC + chn) * HWSZ + p0 + c4 * 4] = v;
            }
            __syncthreads();
        }
    }
}

// ---------------------------------------------------------------------------
// Deformable bilinear sampling: 16 channels/thread (one thread per
// (pixel,group)), bf16x8 gathers, fp32 math.
// C2 row: [value(256) | om: g*32 + {ox,oy pairs(18), m(9), pad(5)}]
// ---------------------------------------------------------------------------
__device__ inline void fma16(float* acc, const __hip_bfloat16* ptr, float wgt)
{
    bf16x8 v0 = *(const bf16x8*)ptr;
    bf16x8 v1 = *(const bf16x8*)(ptr + 8);
#pragma unroll
    for (int j = 0; j < 8; ++j) {
        union { unsigned u; float f; } cv;
        cv.u = ((unsigned)(unsigned short)v0[j]) << 16;
        acc[j] = fmaf(wgt, cv.f, acc[j]);
    }
#pragma unroll
    for (int j = 0; j < 8; ++j) {
        union { unsigned u; float f; } cv;
        cv.u = ((unsigned)(unsigned short)v1[j]) << 16;
        acc[8 + j] = fmaf(wgt, cv.f, acc[8 + j]);
    }
}

__global__ __launch_bounds__(256) void dcn_sample_k(
    const __hip_bfloat16* __restrict__ C2, __hip_bfloat16* __restrict__ accb)
{
    const int idx = blockIdx.x * 256 + threadIdx.x;
    const int g = idx & 15;
    const int mp = idx >> 4;  // n*HW + p
    const int p = mp % HWSZ;
    const int n = mp / HWSZ;
    const int y = p / WW, x = p % WW;

    const unsigned* omw =
        (const unsigned*)(C2 + (size_t)mp * NCAT + 256 + g * 32);
    const __hip_bfloat16* vb =
        C2 + (size_t)n * HWSZ * NCAT + g * 16;

    // masks: bytes 36..55 -> u32 words 9..13
    float mk[9];
    {
        unsigned mw[5];
#pragma unroll
        for (int i = 0; i < 5; ++i) mw[i] = omw[9 + i];
#pragma unroll
        for (int i = 0; i < 9; ++i) {
            unsigned w16 = (i & 1) ? (mw[i >> 1] >> 16) : (mw[i >> 1] & 0xffffu);
            union { unsigned u; float f; } cv; cv.u = w16 << 16;
            mk[i] = cv.f;
        }
    }

    float acc[16] = {};
#pragma unroll
    for (int k = 0; k < 9; ++k) {
        unsigned ow = omw[k];
        union { unsigned u; float f; } cx, cy;
        cx.u = (ow & 0xffffu) << 16;   // ox
        cy.u = ow & 0xffff0000u;       // oy
        float px = (float)(x - 1 + (k % 3)) + cx.f;
        float py = (float)(y - 1 + (k / 3)) + cy.f;
        float fx = floorf(px), fy = floorf(py);
        float wx = px - fx, wy = py - fy;
        int x0 = (int)fx, y0 = (int)fy;
        int x1 = x0 + 1, y1 = y0 + 1;
        float ax0 = ((unsigned)x0 < (unsigned)WW) ? (1.f - wx) : 0.f;
        float ax1 = ((unsigned)x1 < (unsigned)WW) ? wx : 0.f;
        float ay0 = ((unsigned)y0 < (unsigned)HH) ? mk[k] * (1.f - wy) : 0.f;
        float ay1 = ((unsigned)y1 < (unsigned)HH) ? mk[k] * wy : 0.f;
        int xc0 = min(max(x0, 0), WW - 1);
        int xc1 = min(max(x1, 0), WW - 1);
        int yc0 = min(max(y0, 0), HH - 1);
        int yc1 = min(max(y1, 0), HH - 1);
        const __hip_bfloat16* r0 = vb + (size_t)(yc0 * WW) * NCAT;
        const __hip_bfloat16* r1 = vb + (size_t)(yc1 * WW) * NCAT;
        fma16(acc, r0 + (size_t)xc0 * NCAT, ay0 * ax0);
        fma16(acc, r0 + (size_t)xc1 * NCAT, ay0 * ax1);
        fma16(acc, r1 + (size_t)xc0 * NCAT, ay1 * ax0);
        fma16(acc, r1 + (size_t)xc1 * NCAT, ay1 * ax1);
    }

    __hip_bfloat16* op = accb + (size_t)mp * CC + g * 16;
    bf16x8 ov0, ov1;
#pragma unroll
    for (int j = 0; j < 8; ++j) {
        __hip_bfloat16 b0 = __float2bfloat16(acc[j]);
        __hip_bfloat16 b1 = __float2bfloat16(acc[8 + j]);
        ov0[j] = *reinterpret_cast<short*>(&b0);
        ov1[j] = *reinterpret_cast<short*>(&b1);
    }
    *(bf16x8*)op = ov0;
    *(bf16x8*)(op + 8) = ov1;
}

// ---------------------------------------------------------------------------
extern "C" void kernel_launch(void* const* d_in, const int* in_sizes, int n_in,
                              void* d_out, int out_size, void* d_ws, size_t ws_size,
                              hipStream_t stream)
{
    const float* x    = (const float*)d_in[0];
    const float* w1   = (const float*)d_in[1];
    const float* bn1g = (const float*)d_in[2];
    const float* bn1b = (const float*)d_in[3];
    const float* bn1m = (const float*)d_in[4];
    const float* bn1v = (const float*)d_in[5];
    const float* wv   = (const float*)d_in[6];
    const float* bv   = (const float*)d_in[7];
    const float* wom  = (const float*)d_in[8];
    const float* bom  = (const float*)d_in[9];
    const float* wo   = (const float*)d_in[10];
    const float* bo   = (const float*)d_in[11];
    const float* bn2g = (const float*)d_in[12];
    const float* bn2b = (const float*)d_in[13];
    const float* bn2m = (const float*)d_in[14];
    const float* bn2v = (const float*)d_in[15];
    float* out = (float*)d_out;

    char* w = (char*)d_ws;
    __hip_bfloat16* xT    = (__hip_bfloat16*)(w);                 // [M][256]
    __hip_bfloat16* hbuf  = (__hip_bfloat16*)(w + 6553600);       // [M][256]
    __hip_bfloat16* C2    = (__hip_bfloat16*)(w + 13107200);      // [M][768]
    __hip_bfloat16* accb  = (__hip_bfloat16*)(w + 32768000);      // [M][256]
    __hip_bfloat16* w1T   = (__hip_bfloat16*)(w + 39321600);      // [256][256]
    __hip_bfloat16* woT   = (__hip_bfloat16*)(w + 39452672);      // [256][256]
    __hip_bfloat16* BcatT = (__hip_bfloat16*)(w + 39583744);      // [768][256]
    float*          bcat  = (float*)(w + 39976960);               // [768]

    dim3 blk(256);

    prep_weights_k<<<dim3(321), blk, 0, stream>>>(
        w1, wv, wom, wo, bv, bom, w1T, BcatT, woT, bcat);
    transpose_x_k<<<dim3(200, 8, 2), blk, 0, stream>>>(x, xT);

    // h = silu(bn1(x @ w1))
    gemm_mfma<1><<<dim3(200, 2), blk, 0, stream>>>(
        (const short*)xT, (const short*)w1T, nullptr,
        bn1g, bn1b, bn1m, bn1v, hbuf, CC);
    // C2 = h @ [wv|wom'] + bcat
    gemm_mfma<0><<<dim3(200, 6), blk, 0, stream>>>(
        (const short*)hbuf, (const short*)BcatT, bcat,
        nullptr, nullptr, nullptr, nullptr, C2, NCAT);
    // deformable sampling -> accb
    dcn_sample_k<<<dim3(MM * 16 / 256), blk, 0, stream>>>(C2, accb);
    // out = NCHW(silu(bn2(accb @ wo + bo)))
    gemm_mfma<2><<<dim3(200, 2), blk, 0, stream>>>(
        (const short*)accb, (const short*)woT, bo,
        bn2g, bn2b, bn2m, bn2v, out, 0);
}

// Round 10
// 148.931 us; speedup vs baseline: 2.1999x; 1.0113x over previous
//
#include <hip/hip_runtime.h>
#include <hip/hip_bf16.h>
#include <math.h>

typedef __attribute__((ext_vector_type(8))) short bf16x8;
typedef __attribute__((ext_vector_type(4))) float f32x4;

#define NB   2
#define CC   256
#define HH   80
#define WW   80
#define HWSZ 6400
#define MM   (NB * HWSZ)   // 12800
#define NCAT 768           // 256 (value) | 512 (om: 16 groups x (27 used + 5 pad))
#define EPSB 1e-5f

// ---------------------------------------------------------------------------
// K1: merged prep — blocks 0..3199: x NCHW -> xT bf16; 3200..3520: weights
// ---------------------------------------------------------------------------
__device__ inline void t32g(const float* __restrict__ in, int inld, int scol0,
                            int ncols, __hip_bfloat16* __restrict__ out,
                            int orow0, int r0, int tid)
{
    __shared__ float tile[32][33];
    int tx = tid & 31, ty = tid >> 5;
#pragma unroll
    for (int i = 0; i < 32; i += 8)
        tile[ty + i][tx] = (tx < ncols)
            ? in[(size_t)(r0 + ty + i) * inld + scol0 + tx] : 0.f;
    __syncthreads();
#pragma unroll
    for (int i = 0; i < 32; i += 8)
        out[(size_t)(orow0 + ty + i) * 256 + r0 + tx] =
            __float2bfloat16(tile[tx][ty + i]);
}

__global__ __launch_bounds__(256) void prep_all_k(
    const float* __restrict__ x,
    const float* __restrict__ w1, const float* __restrict__ wv,
    const float* __restrict__ wom, const float* __restrict__ wo,
    const float* __restrict__ bv, const float* __restrict__ bom,
    __hip_bfloat16* __restrict__ xT,
    __hip_bfloat16* __restrict__ w1T, __hip_bfloat16* __restrict__ BcatT,
    __hip_bfloat16* __restrict__ woT, float* __restrict__ bcat)
{
    int b = blockIdx.x, t = threadIdx.x;
    if (b < 3200) {
        // x transpose: z = image, by = channel block, bx = spatial block
        __shared__ float tile[32][33];
        int z = b / 1600, r = b % 1600;
        int by = r / 200, bx = r % 200;
        const float* inz = x + (size_t)256 * HWSZ * z;
        __hip_bfloat16* outz = xT + (size_t)HWSZ * 256 * z;
        int bc = bx * 32, br = by * 32;
        int tx = t & 31, ty = t >> 5;
#pragma unroll
        for (int i = 0; i < 32; i += 8)
            tile[ty + i][tx] = inz[(size_t)(br + ty + i) * HWSZ + bc + tx];
        __syncthreads();
#pragma unroll
        for (int i = 0; i < 32; i += 8)
            outz[(size_t)(bc + ty + i) * 256 + br + tx] =
                __float2bfloat16(tile[tx][ty + i]);
        return;
    }
    b -= 3200;
    if (b < 64) {
        t32g(w1, 256, (b >> 3) * 32, 32, w1T, (b >> 3) * 32, (b & 7) * 32, t);
    } else if (b < 128) {
        int b2 = b - 64;
        t32g(wv, 256, (b2 >> 3) * 32, 32, BcatT, (b2 >> 3) * 32, (b2 & 7) * 32, t);
    } else if (b < 192) {
        int b2 = b - 128;
        t32g(wo, 256, (b2 >> 3) * 32, 32, woT, (b2 >> 3) * 32, (b2 & 7) * 32, t);
    } else if (b < 320) {
        int b2 = b - 192;
        int g = b2 >> 3, ct = b2 & 7;
        t32g(wom, 432, g * 27, 27, BcatT + 256 * 256, g * 32, ct * 32, t);
    } else {
        bcat[t] = bv[t];
#pragma unroll
        for (int j = 0; j < 2; ++j) {
            int r = j * 256 + t;
            int g = r >> 5, jj = r & 31;
            bcat[256 + r] = (jj < 27) ? bom[g * 27 + jj] : 0.f;
        }
    }
}

// ---------------------------------------------------------------------------
// K2/K3: bf16 MFMA GEMM, 64x128 tile, BK=64, 4 waves (2x2), K=256, 2-phase
// (verified round 9). EPI 0: +bias bf16; EPI 1: BN+SiLU bf16.
// ---------------------------------------------------------------------------
template <int EPI>
__global__ __launch_bounds__(256) void gemm_mfma(
    const short* __restrict__ A, const short* __restrict__ Bt,
    const float* __restrict__ bias,
    const float* __restrict__ bng, const float* __restrict__ bnb,
    const float* __restrict__ bnm, const float* __restrict__ bnv,
    void* __restrict__ Cout, int ldC)
{
    __shared__ __align__(16) char smem[49152];
    short* As = (short*)smem;            // [2][64*64]
    short* Bs = (short*)(smem + 16384);  // [2][128*64]

    const int t = threadIdx.x;
    const int w = t >> 6, l = t & 63;
    const int wr = w >> 1, wc = w & 1;
    const int m0 = blockIdx.x * 64, n0 = blockIdx.y * 128;

    f32x4 acc[2][4] = {};

    auto STAGE = [&](int b, int k0) {
        short* AsB = As + b * 4096;
        short* BsB = Bs + b * 8192;
#pragma unroll
        for (int i = 0; i < 2; ++i) {
            int s = (w << 1) + i;
            int c = (s << 6) + l;
            int row = c >> 3, ch = c & 7;
            const short* ga = A + (size_t)(m0 + row) * 256 + k0 + (ch << 3);
            __builtin_amdgcn_global_load_lds(
                (const __attribute__((address_space(1))) void*)ga,
                (__attribute__((address_space(3))) void*)(AsB + (s << 9)), 16, 0, 0);
        }
#pragma unroll
        for (int i = 0; i < 4; ++i) {
            int s = (w << 2) + i;
            int c = (s << 6) + l;
            int row = c >> 3, ch = c & 7;
            const short* gb = Bt + (size_t)(n0 + row) * 256 + k0 + (ch << 3);
            __builtin_amdgcn_global_load_lds(
                (const __attribute__((address_space(1))) void*)gb,
                (__attribute__((address_space(3))) void*)(BsB + (s << 9)), 16, 0, 0);
        }
    };

    auto COMPUTE = [&](int b) {
        const short* AsB = As + b * 4096;
        const short* BsB = Bs + b * 8192;
#pragma unroll
        for (int kk = 0; kk < 2; ++kk) {
            bf16x8 af[2], bfr[4];
#pragma unroll
            for (int mi = 0; mi < 2; ++mi)
                af[mi] = *(const bf16x8*)(AsB + (wr * 32 + mi * 16 + (l & 15)) * 64 +
                                          kk * 32 + ((l >> 4) << 3));
#pragma unroll
            for (int ni = 0; ni < 4; ++ni)
                bfr[ni] = *(const bf16x8*)(BsB + (wc * 64 + ni * 16 + (l & 15)) * 64 +
                                           kk * 32 + ((l >> 4) << 3));
#pragma unroll
            for (int mi = 0; mi < 2; ++mi)
#pragma unroll
                for (int ni = 0; ni < 4; ++ni)
                    acc[mi][ni] = __builtin_amdgcn_mfma_f32_16x16x32_bf16(
                        af[mi], bfr[ni], acc[mi][ni], 0, 0, 0);
        }
    };

    STAGE(0, 0);
    __syncthreads();
#pragma unroll
    for (int tt = 0; tt < 4; ++tt) {
        if (tt < 3) STAGE((tt + 1) & 1, (tt + 1) * 64);
        COMPUTE(tt & 1);
        __syncthreads();
    }

    if (EPI == 0) {
#pragma unroll
        for (int ni = 0; ni < 4; ++ni) {
            int chn = n0 + wc * 64 + ni * 16 + (l & 15);
            float bb = bias[chn];
#pragma unroll
            for (int mi = 0; mi < 2; ++mi) {
                int mbase = m0 + wr * 32 + mi * 16 + ((l >> 4) << 2);
#pragma unroll
                for (int j = 0; j < 4; ++j) {
                    float v = acc[mi][ni][j] + bb;
                    ((__hip_bfloat16*)Cout)[(size_t)(mbase + j) * ldC + chn] =
                        __float2bfloat16(v);
                }
            }
        }
    } else {
#pragma unroll
        for (int ni = 0; ni < 4; ++ni) {
            int chn = n0 + wc * 64 + ni * 16 + (l & 15);
            float mu = bnm[chn], iv = rsqrtf(bnv[chn] + EPSB);
            float gm = bng[chn], bt = bnb[chn];
#pragma unroll
            for (int mi = 0; mi < 2; ++mi) {
                int mbase = m0 + wr * 32 + mi * 16 + ((l >> 4) << 2);
#pragma unroll
                for (int j = 0; j < 4; ++j) {
                    float v = acc[mi][ni][j];
                    v = (v - mu) * iv * gm + bt;
                    v = v / (1.f + __expf(-v));
                    ((__hip_bfloat16*)Cout)[(size_t)(mbase + j) * ldC + chn] =
                        __float2bfloat16(v);
                }
            }
        }
    }
}

// ---------------------------------------------------------------------------
// K4: fused {deformable sampling -> LDS A-tile} + GEMM3 + BN2/SiLU + NCHW out.
// Block: 64 pixels x 256 out-channels, 512 threads (8 waves, 2m x 4n).
// LDS: As [64][256] bf16 (32KB, K-resident) + Bs 2x[256][64] bf16 (64KB dbuf).
// ---------------------------------------------------------------------------
__global__ __launch_bounds__(512) void gemm3_fused_k(
    const __hip_bfloat16* __restrict__ C2, const short* __restrict__ woT,
    const float* __restrict__ bias,
    const float* __restrict__ bng, const float* __restrict__ bnb,
    const float* __restrict__ bnm, const float* __restrict__ bnv,
    float* __restrict__ out)
{
    __shared__ __align__(16) char smem[98304];
    short* As = (short*)smem;            // [64][256]
    short* Bs = (short*)(smem + 32768);  // [2][256*64]

    const int t = threadIdx.x;
    const int w = t >> 6, l = t & 63;
    const int wr = w >> 2, wc = w & 3;   // 2 x 4 waves
    const int m0 = blockIdx.x * 64;
    const int nimg = m0 / HWSZ;          // 6400 % 64 == 0
    const int p0 = m0 % HWSZ;

    auto STAGE_B = [&](int b, int k0) {
        short* BsB = Bs + b * 16384;
#pragma unroll
        for (int i = 0; i < 4; ++i) {
            int c = t + i * 512;           // chunk 0..2047
            int row = c >> 3, ch = c & 7;
            const short* gb = woT + (size_t)row * 256 + k0 + (ch << 3);
            __builtin_amdgcn_global_load_lds(
                (const __attribute__((address_space(1))) void*)gb,
                (__attribute__((address_space(3))) void*)(BsB + ((w << 6) + (i << 9)) * 8),
                16, 0, 0);
        }
    };

    // issue first B tile before sampler math so HBM latency hides under it
    STAGE_B(0, 0);

    // ---- sampler phase: fill As[px][256] (1024 (px,g) tasks, 2 per thread)
#pragma unroll
    for (int it = 0; it < 2; ++it) {
        int task = it * 512 + t;
        int g = task & 15, px = task >> 4;
        int mp = m0 + px;
        int p = mp % HWSZ;
        int y = p / WW, x = p % WW;

        const unsigned* omw =
            (const unsigned*)(C2 + (size_t)mp * NCAT + 256 + g * 32);
        const __hip_bfloat16* vb = C2 + (size_t)nimg * HWSZ * NCAT + g * 16;

        float mk[9];
        {
            unsigned mw[5];
#pragma unroll
            for (int i = 0; i < 5; ++i) mw[i] = omw[9 + i];
#pragma unroll
            for (int i = 0; i < 9; ++i) {
                unsigned w16 = (i & 1) ? (mw[i >> 1] >> 16) : (mw[i >> 1] & 0xffffu);
                union { unsigned u; float f; } cv; cv.u = w16 << 16;
                mk[i] = cv.f;
            }
        }

        float acc[16] = {};
#pragma unroll
        for (int k = 0; k < 9; ++k) {
            unsigned ow = omw[k];
            union { unsigned u; float f; } cx, cy;
            cx.u = (ow & 0xffffu) << 16;
            cy.u = ow & 0xffff0000u;
            float px_ = (float)(x - 1 + (k % 3)) + cx.f;
            float py_ = (float)(y - 1 + (k / 3)) + cy.f;
            float fx = floorf(px_), fy = floorf(py_);
            float wx = px_ - fx, wy = py_ - fy;
            int x0 = (int)fx, y0 = (int)fy;
            int x1 = x0 + 1, y1 = y0 + 1;
            float ax0 = ((unsigned)x0 < (unsigned)WW) ? (1.f - wx) : 0.f;
            float ax1 = ((unsigned)x1 < (unsigned)WW) ? wx : 0.f;
            float ay0 = ((unsigned)y0 < (unsigned)HH) ? mk[k] * (1.f - wy) : 0.f;
            float ay1 = ((unsigned)y1 < (unsigned)HH) ? mk[k] * wy : 0.f;
            int xc0 = min(max(x0, 0), WW - 1);
            int xc1 = min(max(x1, 0), WW - 1);
            int yc0 = min(max(y0, 0), HH - 1);
            int yc1 = min(max(y1, 0), HH - 1);
            const __hip_bfloat16* r0 = vb + (size_t)(yc0 * WW) * NCAT;
            const __hip_bfloat16* r1 = vb + (size_t)(yc1 * WW) * NCAT;
            const __hip_bfloat16* pts[4] = {
                r0 + (size_t)xc0 * NCAT, r0 + (size_t)xc1 * NCAT,
                r1 + (size_t)xc0 * NCAT, r1 + (size_t)xc1 * NCAT };
            float wgt[4] = { ay0 * ax0, ay0 * ax1, ay1 * ax0, ay1 * ax1 };
#pragma unroll
            for (int q = 0; q < 4; ++q) {
                bf16x8 v0 = *(const bf16x8*)pts[q];
                bf16x8 v1 = *(const bf16x8*)(pts[q] + 8);
#pragma unroll
                for (int j = 0; j < 8; ++j) {
                    union { unsigned u; float f; } cv;
                    cv.u = ((unsigned)(unsigned short)v0[j]) << 16;
                    acc[j] = fmaf(wgt[q], cv.f, acc[j]);
                }
#pragma unroll
                for (int j = 0; j < 8; ++j) {
                    union { unsigned u; float f; } cv;
                    cv.u = ((unsigned)(unsigned short)v1[j]) << 16;
                    acc[8 + j] = fmaf(wgt[q], cv.f, acc[8 + j]);
                }
            }
        }

        bf16x8 ov0, ov1;
#pragma unroll
        for (int j = 0; j < 8; ++j) {
            __hip_bfloat16 b0 = __float2bfloat16(acc[j]);
            __hip_bfloat16 b1 = __float2bfloat16(acc[8 + j]);
            ov0[j] = *reinterpret_cast<short*>(&b0);
            ov1[j] = *reinterpret_cast<short*>(&b1);
        }
        *(bf16x8*)(As + px * 256 + g * 16) = ov0;
        *(bf16x8*)(As + px * 256 + g * 16 + 8) = ov1;
    }
    __syncthreads();

    // ---- K-loop: A resident in LDS, B double-buffered
    f32x4 acc[2][4] = {};
#pragma unroll
    for (int tt = 0; tt < 4; ++tt) {
        if (tt < 3) STAGE_B((tt + 1) & 1, (tt + 1) * 64);
        const short* BsB = Bs + (tt & 1) * 16384;
        const int k0 = tt * 64;
#pragma unroll
        for (int kk = 0; kk < 2; ++kk) {
            bf16x8 af[2], bfr[4];
#pragma unroll
            for (int mi = 0; mi < 2; ++mi)
                af[mi] = *(const bf16x8*)(As + (wr * 32 + mi * 16 + (l & 15)) * 256 +
                                          k0 + kk * 32 + ((l >> 4) << 3));
#pragma unroll
            for (int ni = 0; ni < 4; ++ni)
                bfr[ni] = *(const bf16x8*)(BsB + (wc * 64 + ni * 16 + (l & 15)) * 64 +
                                           kk * 32 + ((l >> 4) << 3));
#pragma unroll
            for (int mi = 0; mi < 2; ++mi)
#pragma unroll
                for (int ni = 0; ni < 4; ++ni)
                    acc[mi][ni] = __builtin_amdgcn_mfma_f32_16x16x32_bf16(
                        af[mi], bfr[ni], acc[mi][ni], 0, 0, 0);
        }
        __syncthreads();
    }

    // ---- epilogue: BN2 + SiLU + NCHW fp32 store via LDS transpose
    float(*CtT)[68] = (float(*)[68])smem;  // [64 ch][64 m] (+4 pad)
#pragma unroll
    for (int h2 = 0; h2 < 4; ++h2) {
        if (wc == h2) {
#pragma unroll
            for (int ni = 0; ni < 4; ++ni)
#pragma unroll
                for (int mi = 0; mi < 2; ++mi)
#pragma unroll
                    for (int j = 0; j < 4; ++j)
                        CtT[ni * 16 + (l & 15)]
                           [wr * 32 + mi * 16 + ((l >> 4) << 2) + j] =
                               acc[mi][ni][j];
        }
        __syncthreads();
#pragma unroll
        for (int it = 0; it < 2; ++it) {
            int e4 = it * 512 + t;   // f32x4 idx over [64][16]
            int row = e4 >> 4;
            int c4 = e4 & 15;
            int chn = h2 * 64 + row;
            float bb = bias[chn];
            float mu = bnm[chn], iv = rsqrtf(bnv[chn] + EPSB);
            float gm = bng[chn], bt = bnb[chn];
            f32x4 v = *(f32x4*)&CtT[row][c4 * 4];
#pragma unroll
            for (int j = 0; j < 4; ++j) {
                float u = v[j] + bb;
                u = (u - mu) * iv * gm + bt;
                u = u / (1.f + __expf(-u));
                v[j] = u;
            }
            *(f32x4*)&out[(size_t)(nimg * CC + chn) * HWSZ + p0 + c4 * 4] = v;
        }
        __syncthreads();
    }
}

// ---------------------------------------------------------------------------
extern "C" void kernel_launch(void* const* d_in, const int* in_sizes, int n_in,
                              void* d_out, int out_size, void* d_ws, size_t ws_size,
                              hipStream_t stream)
{
    const float* x    = (const float*)d_in[0];
    const float* w1   = (const float*)d_in[1];
    const float* bn1g = (const float*)d_in[2];
    const float* bn1b = (const float*)d_in[3];
    const float* bn1m = (const float*)d_in[4];
    const float* bn1v = (const float*)d_in[5];
    const float* wv   = (const float*)d_in[6];
    const float* bv   = (const float*)d_in[7];
    const float* wom  = (const float*)d_in[8];
    const float* bom  = (const float*)d_in[9];
    const float* wo   = (const float*)d_in[10];
    const float* bo   = (const float*)d_in[11];
    const float* bn2g = (const float*)d_in[12];
    const float* bn2b = (const float*)d_in[13];
    const float* bn2m = (const float*)d_in[14];
    const float* bn2v = (const float*)d_in[15];
    float* out = (float*)d_out;

    char* w = (char*)d_ws;
    __hip_bfloat16* xT    = (__hip_bfloat16*)(w);                 // [M][256]
    __hip_bfloat16* hbuf  = (__hip_bfloat16*)(w + 6553600);       // [M][256]
    __hip_bfloat16* C2    = (__hip_bfloat16*)(w + 13107200);      // [M][768]
    __hip_bfloat16* w1T   = (__hip_bfloat16*)(w + 39321600);      // [256][256]
    __hip_bfloat16* woT   = (__hip_bfloat16*)(w + 39452672);      // [256][256]
    __hip_bfloat16* BcatT = (__hip_bfloat16*)(w + 39583744);      // [768][256]
    float*          bcat  = (float*)(w + 39976960);               // [768]

    dim3 blk(256);

    // K1: all input/weight reformatting
    prep_all_k<<<dim3(3521), blk, 0, stream>>>(
        x, w1, wv, wom, wo, bv, bom, xT, w1T, BcatT, woT, bcat);

    // K2: h = silu(bn1(x @ w1))
    gemm_mfma<1><<<dim3(200, 2), blk, 0, stream>>>(
        (const short*)xT, (const short*)w1T, nullptr,
        bn1g, bn1b, bn1m, bn1v, hbuf, CC);

    // K3: C2 = h @ [wv|wom'] + bcat
    gemm_mfma<0><<<dim3(200, 6), blk, 0, stream>>>(
        (const short*)hbuf, (const short*)BcatT, bcat,
        nullptr, nullptr, nullptr, nullptr, C2, NCAT);

    // K4: out = NCHW(silu(bn2(sample(C2) @ wo + bo)))
    gemm3_fused_k<<<dim3(200), dim3(512), 0, stream>>>(
        C2, (const short*)woT, bo, bn2g, bn2b, bn2m, bn2v, out);
}